// Round 1
// baseline (2244.254 us; speedup 1.0000x reference)
//
#include <hip/hip_runtime.h>
#include <stdint.h>
#include <math.h>

// ---------------------------------------------------------------------------
// Swin block, MI355X. B=32 H=W=112 C=192 NH=6 hd=32 WS=7 SS=3 -> 8192 windows,
// 49 tokens each, 401408 token-rows total.
// Stages: LN1+shift+partition -> qkv GEMM -> windowed attention -> proj+scatter
//         +residual -> LN2 -> fc1+gelu -> fc2+residual.  All matmuls bf16 MFMA,
//         accumulation fp32; residual stream stays fp32 exact.
// ---------------------------------------------------------------------------

typedef unsigned short u16;
typedef unsigned int   u32;
typedef __bf16 v8bf __attribute__((ext_vector_type(8)));
typedef float  v4f  __attribute__((ext_vector_type(4)));

#define MFMA16(a,b,c) __builtin_amdgcn_mfma_f32_16x16x32_bf16(a,b,c,0,0,0)

#define NTOK 401408L
#define HSTR 77070336L          // elems per q/k/v array (8192*6*49*32)

__device__ __forceinline__ u16 f2bf(float f){
  u32 u = __builtin_bit_cast(u32, f);
  u32 r = u + 0x7FFFu + ((u >> 16) & 1u);   // RNE
  return (u16)(r >> 16);
}

// async global->LDS, 16B per lane. lds = wave-uniform base (HW adds lane*16),
// g = per-lane global address.
__device__ __forceinline__ void async16(void* lds, const void* g){
  __builtin_amdgcn_global_load_lds(
      (__attribute__((address_space(1))) void*)(g),
      (__attribute__((address_space(3))) void*)(lds), 16, 0, 0);
}

// ------------------------------ weight convert -----------------------------
__global__ __launch_bounds__(256) void convk(const float* __restrict__ s,
                                             u16* __restrict__ d, int n){
  int i = blockIdx.x * 256 + threadIdx.x;
  if (i < n) d[i] = f2bf(s[i]);
}

// ----------------------- LayerNorm (optionally gathered) -------------------
// one wave per token; 192 = 64 lanes x 3
template<bool GATHER>
__global__ __launch_bounds__(256)
void ln_kern(const float* __restrict__ x, const float* __restrict__ g,
             const float* __restrict__ b, u16* __restrict__ o){
  const long r  = (long)blockIdx.x * 4 + (threadIdx.x >> 6);
  const int  ln = threadIdx.x & 63;
  const float* src;
  if (GATHER){
    // r = window-order row; gather from shifted position
    const long w  = r / 49; const int nn = (int)(r - w * 49);
    const long bb = w >> 8; const int wl = (int)(w & 255);
    const int  wh = wl >> 4, wwi = wl & 15;
    const int  ii = nn / 7,  jj  = nn - ii * 7;
    int th = wh * 7 + ii + 3;  if (th >= 112) th -= 112;
    int tw = wwi * 7 + jj + 3; if (tw >= 112) tw -= 112;
    src = x + (bb * 12544 + (long)th * 112 + tw) * 192;
  } else {
    src = x + r * 192;
  }
  float v0 = src[ln], v1 = src[ln + 64], v2 = src[ln + 128];
  float sm = v0 + v1 + v2;
  float sq = v0*v0 + v1*v1 + v2*v2;
  #pragma unroll
  for (int d = 1; d < 64; d <<= 1){
    sm += __shfl_xor(sm, d, 64);
    sq += __shfl_xor(sq, d, 64);
  }
  float mean = sm * (1.f/192.f);
  float var  = sq * (1.f/192.f) - mean * mean;
  float rs   = rsqrtf(var + 1e-5f);
  u16* dst = o + r * 192;
  dst[ln]       = f2bf((v0 - mean) * rs * g[ln]       + b[ln]);
  dst[ln + 64]  = f2bf((v1 - mean) * rs * g[ln + 64]  + b[ln + 64]);
  dst[ln + 128] = f2bf((v2 - mean) * rs * g[ln + 128] + b[ln + 128]);
}

// ------------------------------- GEMM (A @ W^T) ----------------------------
// BM=128, BN=64, BK=192 per stage. 4 waves (2x2), each wave 64x32 out.
// LDS rows padded to 200 bf16 (400B) to break the 384B-stride bank conflict;
// staging keeps LDS linear (pad chunk re-reads last 16B of the row).
// EPI: 0 = qkv permuted store, 1 = proj+scatter+residual, 2 = fc1+gelu,
//      3 = fc2 += into d_out.
template<int EPI>
__global__ __launch_bounds__(256)
void gemm_bt(const u16* __restrict__ A, int ldA, long aRowOff,
             const u16* __restrict__ W, int ldW, int K,
             const float* __restrict__ bias,
             u16* __restrict__ ob, float* __restrict__ of,
             const float* __restrict__ xres, long oRowOff){
  __shared__ __align__(16) u16 sA[128 * 200];
  __shared__ __align__(16) u16 sW[64 * 200];
  const int tid = threadIdx.x;
  const int wv = tid >> 6, ln = tid & 63;
  const int lr = ln & 15, lg = ln >> 4;
  const long m0  = (long)blockIdx.x * 128;
  const int col0 = (int)blockIdx.y * 64;
  const int wr = wv >> 1, wc = wv & 1;

  const v4f zf = {0.f, 0.f, 0.f, 0.f};
  v4f acc[4][2];
  #pragma unroll
  for (int m = 0; m < 4; ++m)
    #pragma unroll
    for (int n = 0; n < 2; ++n) acc[m][n] = zf;

  const int nK = K / 192;
  for (int ks = 0; ks < nK; ++ks){
    if (ks) __syncthreads();
    const int k0 = ks * 192;
    // A tile: 128 rows x 25 chunks(16B) = 3200 chunks
    #pragma unroll
    for (int it = 0; it < 12; ++it){
      int c = it * 256 + tid;
      int row = c / 25, kc = c % 25; kc = (kc == 24) ? 23 : kc;
      async16((char*)sA + (size_t)(it * 256 + wv * 64) * 16,
              A + (aRowOff + m0 + row) * (long)ldA + (k0 + kc * 8));
    }
    if (wv < 2){
      int c = 3072 + tid;
      int row = c / 25, kc = c % 25; kc = (kc == 24) ? 23 : kc;
      async16((char*)sA + (size_t)(3072 + wv * 64) * 16,
              A + (aRowOff + m0 + row) * (long)ldA + (k0 + kc * 8));
    }
    // W tile: 64 rows x 25 chunks = 1600 chunks
    #pragma unroll
    for (int it = 0; it < 6; ++it){
      int c = it * 256 + tid;
      int row = c / 25, kc = c % 25; kc = (kc == 24) ? 23 : kc;
      async16((char*)sW + (size_t)(it * 256 + wv * 64) * 16,
              W + (long)(col0 + row) * ldW + (k0 + kc * 8));
    }
    if (wv == 0){
      int c = 1536 + tid;
      int row = c / 25, kc = c % 25; kc = (kc == 24) ? 23 : kc;
      async16((char*)sW + (size_t)1536 * 16,
              W + (long)(col0 + row) * ldW + (k0 + kc * 8));
    }
    __syncthreads();   // drains vmcnt(0) -> staged data visible

    #pragma unroll
    for (int kk = 0; kk < 6; ++kk){
      v8bf af[4], wf[2];
      #pragma unroll
      for (int m = 0; m < 4; ++m)
        af[m] = *(const v8bf*)&sA[(wr*64 + m*16 + lr) * 200 + kk*32 + lg*8];
      #pragma unroll
      for (int n = 0; n < 2; ++n)
        wf[n] = *(const v8bf*)&sW[(wc*32 + n*16 + lr) * 200 + kk*32 + lg*8];
      #pragma unroll
      for (int m = 0; m < 4; ++m)
        #pragma unroll
        for (int n = 0; n < 2; ++n)
          acc[m][n] = MFMA16(af[m], wf[n], acc[m][n]);
    }
  }

  // epilogue.  D layout: row = 4*lg + r, col = lr  (m89-verified)
  #pragma unroll
  for (int m = 0; m < 4; ++m){
    #pragma unroll
    for (int n = 0; n < 2; ++n){
      #pragma unroll
      for (int r = 0; r < 4; ++r){
        const long lrow = m0 + wr*64 + m*16 + lg*4 + r;
        const int  col  = col0 + wc*32 + n*16 + lr;
        float val = acc[m][n][r] + bias[col];
        if (EPI == 0){
          // qkv: col -> (which, head, d); store bf16 in [w][h][n][d] layout
          int which = col / 192, rem = col % 192;
          int hh = rem >> 5, dd = rem & 31;
          if (which == 0) val *= 0.17677669529663687f;  // hd^-0.5
          long wdx = lrow / 49; int nn = (int)(lrow - wdx * 49);
          ob[(long)which * HSTR + ((wdx*6 + hh)*49 + nn)*32 + dd] = f2bf(val);
        } else if (EPI == 1){
          // proj: window-reverse + roll-back scatter + residual
          long wdx = lrow / 49; int nn = (int)(lrow - wdx * 49);
          long bb = wdx >> 8; int wl = (int)(wdx & 255);
          int wh = wl >> 4, wwi = wl & 15;
          int ii = nn / 7, jj = nn - ii * 7;
          int th = wh * 7 + ii + 3;  if (th >= 112) th -= 112;
          int tw = wwi * 7 + jj + 3; if (tw >= 112) tw -= 112;
          long adr = (bb * 12544 + (long)th * 112 + tw) * 192 + col;
          of[adr] = xres[adr] + val;
        } else if (EPI == 2){
          float gg = 0.5f * val * (1.0f + erff(val * 0.7071067811865475f));
          ob[lrow * 768 + col] = f2bf(gg);
        } else {
          of[(oRowOff + lrow) * 192 + col] += val;
        }
      }
    }
  }
}

// ------------------------------- attention ---------------------------------
// one wave per (window, head); 4 waves / block.  49 padded to 64.
__global__ __launch_bounds__(256)
void attn_k(const u16* __restrict__ qkv, const float* __restrict__ rpbT,
            u16* __restrict__ aout){
  __shared__ __align__(16) u16 plds[4][64 * 72];  // P, rows padded to 72
  __shared__ __align__(16) u16 vlds[4][32 * 72];  // V^T [d][tok]
  const int wv = threadIdx.x >> 6, ln = threadIdx.x & 63;
  const int lr = ln & 15, lg = ln >> 4;
  const long gid = (long)blockIdx.x * 4 + wv;     // < 49152
  const long w = gid / 6; const int h = (int)(gid - w * 6);
  const u16* qb = qkv + (w * 6 + h) * 1568;
  const u16* kb = qb + HSTR;
  const u16* vb = kb + HSTR;

  // S = q @ k^T  (both frags use k-map 8*lg+e; consistent pair => correct)
  v8bf aq[4], bk[4];
  #pragma unroll
  for (int m = 0; m < 4; ++m) aq[m] = *(const v8bf*)(qb + (m*16 + lr)*32 + lg*8);
  #pragma unroll
  for (int n = 0; n < 4; ++n) bk[n] = *(const v8bf*)(kb + (n*16 + lr)*32 + lg*8);
  const v4f zf = {0.f, 0.f, 0.f, 0.f};
  v4f s[4][4];
  #pragma unroll
  for (int m = 0; m < 4; ++m)
    #pragma unroll
    for (int n = 0; n < 4; ++n) s[m][n] = zf;
  #pragma unroll
  for (int m = 0; m < 4; ++m)
    #pragma unroll
    for (int n = 0; n < 4; ++n) s[m][n] = MFMA16(aq[m], bk[n], s[m][n]);

  // stage V transposed into LDS; zero the 49..63 pad (P there is 0 anyway,
  // but must not be NaN garbage)
  #pragma unroll 4
  for (int i = 0; i < 32; ++i){
    int t = i * 64 + ln; int tok = t >> 5, dd = t & 31;
    u16 vvv = (t < 1568) ? vb[t] : (u16)0;
    vlds[wv][dd * 72 + tok] = vvv;
  }

  // mask/bias geometry
  const int wl = (int)(w & 255); const int whh = wl >> 4, wwi = wl & 15;
  int clab[4];
  #pragma unroll
  for (int n = 0; n < 4; ++n){
    int col = n * 16 + lr; int c2 = col < 49 ? col : 48;
    int i2 = c2 / 7, j2 = c2 - i2 * 7;
    int gh = whh * 7 + i2, gw = wwi * 7 + j2;
    int lh = gh < 105 ? 0 : (gh < 109 ? 1 : 2);
    int lw = gw < 105 ? 0 : (gw < 109 ? 1 : 2);
    clab[n] = lh * 3 + lw;
  }

  float rsum[4][4];
  #pragma unroll
  for (int m = 0; m < 4; ++m){
    #pragma unroll
    for (int r = 0; r < 4; ++r){
      const int row = m * 16 + lg * 4 + r;
      const bool rvalid = row < 49;
      int rc = rvalid ? row : 48;
      int i1 = rc / 7, j1 = rc - i1 * 7;
      int gh = whh * 7 + i1, gw = wwi * 7 + j1;
      int lh = gh < 105 ? 0 : (gh < 109 ? 1 : 2);
      int lw = gw < 105 ? 0 : (gw < 109 ? 1 : 2);
      int lab1 = lh * 3 + lw;
      float sv[4];
      #pragma unroll
      for (int n = 0; n < 4; ++n){
        int col = n * 16 + lr;
        float xv = s[m][n][r];
        if (col < 49 && rvalid){
          int i2 = col / 7, j2 = col - i2 * 7;
          int ridx = (i1 - i2 + 6) * 13 + (j1 - j2 + 6);
          xv += rpbT[ridx * 6 + h];
          if (clab[n] != lab1) xv -= 100.f;
        }
        if (col >= 49) xv = -1e30f;
        sv[n] = xv;
      }
      float mx = fmaxf(fmaxf(sv[0], sv[1]), fmaxf(sv[2], sv[3]));
      #pragma unroll
      for (int d = 1; d < 16; d <<= 1) mx = fmaxf(mx, __shfl_xor(mx, d, 64));
      float p0 = __expf(sv[0] - mx), p1 = __expf(sv[1] - mx);
      float p2 = __expf(sv[2] - mx), p3 = __expf(sv[3] - mx);
      float sm = p0 + p1 + p2 + p3;
      #pragma unroll
      for (int d = 1; d < 16; d <<= 1) sm += __shfl_xor(sm, d, 64);
      rsum[m][r] = sm;                 // normalize at the end (out rows match)
      plds[wv][row * 72 + 0 * 16 + lr] = f2bf(p0);
      plds[wv][row * 72 + 1 * 16 + lr] = f2bf(p1);
      plds[wv][row * 72 + 2 * 16 + lr] = f2bf(p2);
      plds[wv][row * 72 + 3 * 16 + lr] = f2bf(p3);
    }
  }

  // out = P @ V  (K = 64 padded tokens, 2 k-steps)
  v8bf pa[4][2], bv[2][2];
  #pragma unroll
  for (int m2 = 0; m2 < 4; ++m2)
    #pragma unroll
    for (int ks = 0; ks < 2; ++ks)
      pa[m2][ks] = *(const v8bf*)&plds[wv][(m2*16 + lr)*72 + ks*32 + lg*8];
  #pragma unroll
  for (int n2 = 0; n2 < 2; ++n2)
    #pragma unroll
    for (int ks = 0; ks < 2; ++ks)
      bv[n2][ks] = *(const v8bf*)&vlds[wv][(n2*16 + lr)*72 + ks*32 + lg*8];
  v4f o[4][2];
  #pragma unroll
  for (int m2 = 0; m2 < 4; ++m2)
    #pragma unroll
    for (int n2 = 0; n2 < 2; ++n2) o[m2][n2] = zf;
  #pragma unroll
  for (int ks = 0; ks < 2; ++ks)
    #pragma unroll
    for (int m2 = 0; m2 < 4; ++m2)
      #pragma unroll
      for (int n2 = 0; n2 < 2; ++n2)
        o[m2][n2] = MFMA16(pa[m2][ks], bv[n2][ks], o[m2][n2]);

  #pragma unroll
  for (int m2 = 0; m2 < 4; ++m2){
    #pragma unroll
    for (int n2 = 0; n2 < 2; ++n2){
      #pragma unroll
      for (int r = 0; r < 4; ++r){
        int row = m2 * 16 + lg * 4 + r;
        if (row < 49){
          float val = o[m2][n2][r] / rsum[m2][r];
          aout[(w * 49 + row) * 192 + h * 32 + n2 * 16 + lr] = f2bf(val);
        }
      }
    }
  }
}

// ------------------------------ launcher -----------------------------------
extern "C" void kernel_launch(void* const* d_in, const int* in_sizes, int n_in,
                              void* d_out, int out_size, void* d_ws, size_t ws_size,
                              hipStream_t stream){
  const float* x     = (const float*)d_in[0];
  const float* n1g   = (const float*)d_in[1];
  const float* n1b   = (const float*)d_in[2];
  const float* qkvw  = (const float*)d_in[3];
  const float* qkvb  = (const float*)d_in[4];
  const float* rpb   = (const float*)d_in[5];
  const float* projw = (const float*)d_in[6];
  const float* projb = (const float*)d_in[7];
  const float* n2g   = (const float*)d_in[8];
  const float* n2b   = (const float*)d_in[9];
  const float* fc1w  = (const float*)d_in[10];
  const float* fc1b  = (const float*)d_in[11];
  const float* fc2w  = (const float*)d_in[12];
  const float* fc2b  = (const float*)d_in[13];
  float* out = (float*)d_out;

  // d_ws layout (617.5 MB):
  //   bufA @ 0        : qkv (462.4MB) -> later h1 chunks (308.3MB)
  //   bufB @ 462.4MB  : xw -> attn_out -> xln2 (154.1MB)
  //   weights @ 616.6MB : bf16 copies (~0.9MB)
  char* ws  = (char*)d_ws;
  u16* bufA = (u16*)ws;
  u16* bufB = (u16*)(ws + 462422016L);
  u16* wq   = (u16*)(ws + 616562688L);
  u16* wp   = wq + 110592;
  u16* w1   = wp + 36864;
  u16* w2   = w1 + 147456;

  convk<<<432, 256, 0, stream>>>(qkvw,  wq, 110592);
  convk<<<144, 256, 0, stream>>>(projw, wp, 36864);
  convk<<<576, 256, 0, stream>>>(fc1w,  w1, 147456);
  convk<<<576, 256, 0, stream>>>(fc2w,  w2, 147456);

  // LN1 + shift + window partition
  ln_kern<true><<<100352, 256, 0, stream>>>(x, n1g, n1b, bufB);
  // qkv (M=401408, N=576, K=192) -> permuted q,k,v
  gemm_bt<0><<<dim3(3136, 9), 256, 0, stream>>>(bufB, 192, 0, wq, 192, 192,
                                                qkvb, bufA, nullptr, nullptr, 0);
  // windowed attention
  attn_k<<<12288, 256, 0, stream>>>(bufA, rpb, bufB);
  // proj (N=192) + scatter + residual -> d_out
  gemm_bt<1><<<dim3(3136, 3), 256, 0, stream>>>(bufB, 192, 0, wp, 192, 192,
                                                projb, nullptr, out, x, 0);
  // LN2
  ln_kern<false><<<100352, 256, 0, stream>>>(out, n2g, n2b, bufB);
  // MLP in 2 token-chunks (h1 chunk reuses bufA)
  for (int c = 0; c < 2; ++c){
    long off = (long)c * 200704;
    gemm_bt<2><<<dim3(1568, 12), 256, 0, stream>>>(bufB, 192, off, w1, 192, 192,
                                                   fc1b, bufA, nullptr, nullptr, 0);
    gemm_bt<3><<<dim3(1568, 3), 256, 0, stream>>>(bufA, 768, 0, w2, 768, 768,
                                                  fc2b, nullptr, out, nullptr, off);
  }
}

// Round 2
// 1956.659 us; speedup vs baseline: 1.1470x; 1.1470x over previous
//
#include <hip/hip_runtime.h>
#include <stdint.h>
#include <math.h>

// ---------------------------------------------------------------------------
// Swin block, MI355X. B=32 H=W=112 C=192 NH=6 hd=32 WS=7 SS=3 -> 8192 windows,
// 49 tokens each, 401408 token-rows total.
// Stages: LN1+shift+partition -> qkv GEMM -> windowed attention -> proj+scatter
//         +residual -> LN2 -> fc1+gelu -> fc2+residual.  All matmuls bf16 MFMA,
//         accumulation fp32; residual stream stays fp32 exact.
// R1: attention rewritten — fused bias+mask table (built in d_out scratch),
//     V fragments straight from global (k-permuted), packed P stores, batched
//     ILP softmax, LDS 55->37KB.
// ---------------------------------------------------------------------------

typedef unsigned short u16;
typedef unsigned int   u32;
typedef __bf16 v8bf __attribute__((ext_vector_type(8)));
typedef float  v4f  __attribute__((ext_vector_type(4)));
typedef u16    v8u16 __attribute__((ext_vector_type(8)));
typedef u16    v4u16 __attribute__((ext_vector_type(4)));

#define MFMA16(a,b,c) __builtin_amdgcn_mfma_f32_16x16x32_bf16(a,b,c,0,0,0)

#define NTOK 401408L
#define HSTR 77070336L          // elems per q/k/v array (8192*6*49*32)

__device__ __forceinline__ u16 f2bf(float f){
  u32 u = __builtin_bit_cast(u32, f);
  u32 r = u + 0x7FFFu + ((u >> 16) & 1u);   // RNE
  return (u16)(r >> 16);
}

// async global->LDS, 16B per lane. lds = wave-uniform base (HW adds lane*16),
// g = per-lane global address.
__device__ __forceinline__ void async16(void* lds, const void* g){
  __builtin_amdgcn_global_load_lds(
      (__attribute__((address_space(1))) void*)(g),
      (__attribute__((address_space(3))) void*)(lds), 16, 0, 0);
}

// ------------------------------ weight convert -----------------------------
__global__ __launch_bounds__(256) void convk(const float* __restrict__ s,
                                             u16* __restrict__ d, int n){
  int i = blockIdx.x * 256 + threadIdx.x;
  if (i < n) d[i] = f2bf(s[i]);
}

// -------------------- fused rel-pos-bias + shift-mask table ----------------
// bmt[cls][h][row][col], cls: 0 interior, 1 right edge, 2 bottom edge, 3 corner
// rows/cols >= 49 get -1e30 (softmax-neutral pad).
__global__ __launch_bounds__(256)
void bmt_k(const float* __restrict__ rpb, float* __restrict__ bmt){
  int idx = blockIdx.x * 256 + threadIdx.x;      // 98304 total
  int col = idx & 63, row = (idx >> 6) & 63;
  int t = idx >> 12; int h = t % 6, cls = t / 6;
  float v;
  if (row >= 49 || col >= 49){
    v = -1e30f;
  } else {
    int i1 = row / 7, j1 = row - i1 * 7;
    int i2 = col / 7, j2 = col - i2 * 7;
    int ridx = (i1 - i2 + 6) * 13 + (j1 - j2 + 6);
    v = rpb[ridx * 6 + h];
    int lh1 = (cls & 2) ? (i1 < 4 ? 1 : 2) : 0;
    int lw1 = (cls & 1) ? (j1 < 4 ? 1 : 2) : 0;
    int lh2 = (cls & 2) ? (i2 < 4 ? 1 : 2) : 0;
    int lw2 = (cls & 1) ? (j2 < 4 ? 1 : 2) : 0;
    if (lh1 * 3 + lw1 != lh2 * 3 + lw2) v -= 100.f;
  }
  bmt[idx] = v;
}

// ----------------------- LayerNorm (optionally gathered) -------------------
// one wave per token; 192 = 64 lanes x 3
template<bool GATHER>
__global__ __launch_bounds__(256)
void ln_kern(const float* __restrict__ x, const float* __restrict__ g,
             const float* __restrict__ b, u16* __restrict__ o){
  const long r  = (long)blockIdx.x * 4 + (threadIdx.x >> 6);
  const int  ln = threadIdx.x & 63;
  const float* src;
  if (GATHER){
    const long w  = r / 49; const int nn = (int)(r - w * 49);
    const long bb = w >> 8; const int wl = (int)(w & 255);
    const int  wh = wl >> 4, wwi = wl & 15;
    const int  ii = nn / 7,  jj  = nn - ii * 7;
    int th = wh * 7 + ii + 3;  if (th >= 112) th -= 112;
    int tw = wwi * 7 + jj + 3; if (tw >= 112) tw -= 112;
    src = x + (bb * 12544 + (long)th * 112 + tw) * 192;
  } else {
    src = x + r * 192;
  }
  float v0 = src[ln], v1 = src[ln + 64], v2 = src[ln + 128];
  float sm = v0 + v1 + v2;
  float sq = v0*v0 + v1*v1 + v2*v2;
  #pragma unroll
  for (int d = 1; d < 64; d <<= 1){
    sm += __shfl_xor(sm, d, 64);
    sq += __shfl_xor(sq, d, 64);
  }
  float mean = sm * (1.f/192.f);
  float var  = sq * (1.f/192.f) - mean * mean;
  float rs   = rsqrtf(var + 1e-5f);
  u16* dst = o + r * 192;
  dst[ln]       = f2bf((v0 - mean) * rs * g[ln]       + b[ln]);
  dst[ln + 64]  = f2bf((v1 - mean) * rs * g[ln + 64]  + b[ln + 64]);
  dst[ln + 128] = f2bf((v2 - mean) * rs * g[ln + 128] + b[ln + 128]);
}

// ------------------------------- GEMM (A @ W^T) ----------------------------
// BM=128, BN=64, BK=192 per stage. 4 waves (2x2), each wave 64x32 out.
// LDS rows padded to 200 bf16 (400B). EPI: 0 = qkv permuted store,
// 1 = proj+scatter+residual, 2 = fc1+gelu, 3 = fc2 += into d_out.
template<int EPI>
__global__ __launch_bounds__(256)
void gemm_bt(const u16* __restrict__ A, int ldA, long aRowOff,
             const u16* __restrict__ W, int ldW, int K,
             const float* __restrict__ bias,
             u16* __restrict__ ob, float* __restrict__ of,
             const float* __restrict__ xres, long oRowOff){
  __shared__ __align__(16) u16 sA[128 * 200];
  __shared__ __align__(16) u16 sW[64 * 200];
  const int tid = threadIdx.x;
  const int wv = tid >> 6, ln = tid & 63;
  const int lr = ln & 15, lg = ln >> 4;
  const long m0  = (long)blockIdx.x * 128;
  const int col0 = (int)blockIdx.y * 64;
  const int wr = wv >> 1, wc = wv & 1;

  const v4f zf = {0.f, 0.f, 0.f, 0.f};
  v4f acc[4][2];
  #pragma unroll
  for (int m = 0; m < 4; ++m)
    #pragma unroll
    for (int n = 0; n < 2; ++n) acc[m][n] = zf;

  const int nK = K / 192;
  for (int ks = 0; ks < nK; ++ks){
    if (ks) __syncthreads();
    const int k0 = ks * 192;
    #pragma unroll
    for (int it = 0; it < 12; ++it){
      int c = it * 256 + tid;
      int row = c / 25, kc = c % 25; kc = (kc == 24) ? 23 : kc;
      async16((char*)sA + (size_t)(it * 256 + wv * 64) * 16,
              A + (aRowOff + m0 + row) * (long)ldA + (k0 + kc * 8));
    }
    if (wv < 2){
      int c = 3072 + tid;
      int row = c / 25, kc = c % 25; kc = (kc == 24) ? 23 : kc;
      async16((char*)sA + (size_t)(3072 + wv * 64) * 16,
              A + (aRowOff + m0 + row) * (long)ldA + (k0 + kc * 8));
    }
    #pragma unroll
    for (int it = 0; it < 6; ++it){
      int c = it * 256 + tid;
      int row = c / 25, kc = c % 25; kc = (kc == 24) ? 23 : kc;
      async16((char*)sW + (size_t)(it * 256 + wv * 64) * 16,
              W + (long)(col0 + row) * ldW + (k0 + kc * 8));
    }
    if (wv == 0){
      int c = 1536 + tid;
      int row = c / 25, kc = c % 25; kc = (kc == 24) ? 23 : kc;
      async16((char*)sW + (size_t)1536 * 16,
              W + (long)(col0 + row) * ldW + (k0 + kc * 8));
    }
    __syncthreads();

    #pragma unroll
    for (int kk = 0; kk < 6; ++kk){
      v8bf af[4], wf[2];
      #pragma unroll
      for (int m = 0; m < 4; ++m)
        af[m] = *(const v8bf*)&sA[(wr*64 + m*16 + lr) * 200 + kk*32 + lg*8];
      #pragma unroll
      for (int n = 0; n < 2; ++n)
        wf[n] = *(const v8bf*)&sW[(wc*32 + n*16 + lr) * 200 + kk*32 + lg*8];
      #pragma unroll
      for (int m = 0; m < 4; ++m)
        #pragma unroll
        for (int n = 0; n < 2; ++n)
          acc[m][n] = MFMA16(af[m], wf[n], acc[m][n]);
    }
  }

  // epilogue.  D layout: row = 4*lg + r, col = lr
  #pragma unroll
  for (int m = 0; m < 4; ++m){
    #pragma unroll
    for (int n = 0; n < 2; ++n){
      #pragma unroll
      for (int r = 0; r < 4; ++r){
        const long lrow = m0 + wr*64 + m*16 + lg*4 + r;
        const int  col  = col0 + wc*32 + n*16 + lr;
        float val = acc[m][n][r] + bias[col];
        if (EPI == 0){
          int which = col / 192, rem = col % 192;
          int hh = rem >> 5, dd = rem & 31;
          if (which == 0) val *= 0.17677669529663687f;  // hd^-0.5
          long wdx = lrow / 49; int nn = (int)(lrow - wdx * 49);
          ob[(long)which * HSTR + ((wdx*6 + hh)*49 + nn)*32 + dd] = f2bf(val);
        } else if (EPI == 1){
          long wdx = lrow / 49; int nn = (int)(lrow - wdx * 49);
          long bb = wdx >> 8; int wl = (int)(wdx & 255);
          int wh = wl >> 4, wwi = wl & 15;
          int ii = nn / 7, jj = nn - ii * 7;
          int th = wh * 7 + ii + 3;  if (th >= 112) th -= 112;
          int tw = wwi * 7 + jj + 3; if (tw >= 112) tw -= 112;
          long adr = (bb * 12544 + (long)th * 112 + tw) * 192 + col;
          of[adr] = xres[adr] + val;
        } else if (EPI == 2){
          float gg = 0.5f * val * (1.0f + erff(val * 0.7071067811865475f));
          ob[lrow * 768 + col] = f2bf(gg);
        } else {
          of[(oRowOff + lrow) * 192 + col] += val;
        }
      }
    }
  }
}

// ------------------------------- attention ---------------------------------
// one wave per (window, head); 4 waves / block.  49 padded to 64.
// S layout per tile (m,n): q-row = m*16 + lg*4 + r, k-col = n*16 + lr.
// P stored to LDS with packed column-permutation pos = lr*4 + n; the same
// token permutation t(kp) = (kp>>2) + (kp&3)*16 is applied to the V fragment
// k-index, so the PV contraction is invariant.
__global__ __launch_bounds__(256, 3)
void attn_k(const u16* __restrict__ qkv, const float* __restrict__ bmt,
            u16* __restrict__ aout){
  __shared__ __align__(16) u16 plds[4][64 * 72];
  const int wv = threadIdx.x >> 6, ln = threadIdx.x & 63;
  const int lr = ln & 15, lg = ln >> 4;
  const long gid = (long)blockIdx.x * 4 + wv;     // < 49152
  const long w = gid / 6; const int h = (int)(gid - w * 6);
  const u16* qb = qkv + (w * 6 + h) * 1568;
  const u16* kb = qb + HSTR;
  const u16* vb = kb + HSTR;

  // V fragments straight from global, k-permuted (toks 49..63 hit following
  // valid memory; multiplied by P==0 so harmless).
  v8u16 bvu[2][2];
  #pragma unroll
  for (int n2 = 0; n2 < 2; ++n2)
    #pragma unroll
    for (int ks = 0; ks < 2; ++ks)
      #pragma unroll
      for (int e = 0; e < 8; ++e){
        int kp = ks * 32 + lg * 8 + e;
        int t  = (kp >> 2) + (kp & 3) * 16;
        bvu[n2][ks][e] = vb[t * 32 + n2 * 16 + lr];
      }

  // Q.K^T
  v8bf aq[4], bk4[4];
  #pragma unroll
  for (int m = 0; m < 4; ++m) aq[m]  = *(const v8bf*)(qb + (m*16 + lr)*32 + lg*8);
  #pragma unroll
  for (int n = 0; n < 4; ++n) bk4[n] = *(const v8bf*)(kb + (n*16 + lr)*32 + lg*8);
  const v4f zf = {0.f, 0.f, 0.f, 0.f};
  v4f s[4][4];
  #pragma unroll
  for (int m = 0; m < 4; ++m)
    #pragma unroll
    for (int n = 0; n < 4; ++n) s[m][n] = zf;
  #pragma unroll
  for (int m = 0; m < 4; ++m)
    #pragma unroll
    for (int n = 0; n < 4; ++n) s[m][n] = MFMA16(aq[m], bk4[n], s[m][n]);

  // + fused bias/mask table (L2-resident)
  const int wl = (int)(w & 255);
  const int cls = (((wl >> 4) == 15) ? 2 : 0) | (((wl & 15) == 15) ? 1 : 0);
  const float* bm = bmt + ((long)(cls * 6 + h) << 12);
  #pragma unroll
  for (int m = 0; m < 4; ++m)
    #pragma unroll
    for (int n = 0; n < 4; ++n)
      #pragma unroll
      for (int r = 0; r < 4; ++r)
        s[m][n][r] += bm[(m*16 + lg*4 + r) * 64 + n*16 + lr];

  // batched softmax (16 independent rows -> ILP across shuffle rounds)
  float mx[4][4], rs_[4][4];
  #pragma unroll
  for (int m = 0; m < 4; ++m)
    #pragma unroll
    for (int r = 0; r < 4; ++r)
      mx[m][r] = fmaxf(fmaxf(s[m][0][r], s[m][1][r]), fmaxf(s[m][2][r], s[m][3][r]));
  #pragma unroll
  for (int d = 1; d < 16; d <<= 1)
    #pragma unroll
    for (int m = 0; m < 4; ++m)
      #pragma unroll
      for (int r = 0; r < 4; ++r)
        mx[m][r] = fmaxf(mx[m][r], __shfl_xor(mx[m][r], d, 64));
  #pragma unroll
  for (int m = 0; m < 4; ++m)
    #pragma unroll
    for (int r = 0; r < 4; ++r){
      float a0 = __expf(s[m][0][r] - mx[m][r]);
      float a1 = __expf(s[m][1][r] - mx[m][r]);
      float a2 = __expf(s[m][2][r] - mx[m][r]);
      float a3 = __expf(s[m][3][r] - mx[m][r]);
      s[m][0][r] = a0; s[m][1][r] = a1; s[m][2][r] = a2; s[m][3][r] = a3;
      rs_[m][r] = (a0 + a1) + (a2 + a3);
    }
  #pragma unroll
  for (int d = 1; d < 16; d <<= 1)
    #pragma unroll
    for (int m = 0; m < 4; ++m)
      #pragma unroll
      for (int r = 0; r < 4; ++r)
        rs_[m][r] += __shfl_xor(rs_[m][r], d, 64);
  #pragma unroll
  for (int m = 0; m < 4; ++m)
    #pragma unroll
    for (int r = 0; r < 4; ++r)
      rs_[m][r] = 1.0f / rs_[m][r];

  // packed P store: one b64 per (m,r); pos = lr*4 + n
  #pragma unroll
  for (int m = 0; m < 4; ++m)
    #pragma unroll
    for (int r = 0; r < 4; ++r){
      int row = m*16 + lg*4 + r;
      v4u16 pk;
      pk[0] = f2bf(s[m][0][r]); pk[1] = f2bf(s[m][1][r]);
      pk[2] = f2bf(s[m][2][r]); pk[3] = f2bf(s[m][3][r]);
      *(v4u16*)&plds[wv][row * 72 + lr * 4] = pk;
    }

  // P @ V
  v8bf pa[4][2];
  #pragma unroll
  for (int m2 = 0; m2 < 4; ++m2)
    #pragma unroll
    for (int ks = 0; ks < 2; ++ks)
      pa[m2][ks] = *(const v8bf*)&plds[wv][(m2*16 + lr) * 72 + ks*32 + lg*8];
  v4f o[4][2];
  #pragma unroll
  for (int m2 = 0; m2 < 4; ++m2)
    #pragma unroll
    for (int n2 = 0; n2 < 2; ++n2) o[m2][n2] = zf;
  #pragma unroll
  for (int ks = 0; ks < 2; ++ks)
    #pragma unroll
    for (int m2 = 0; m2 < 4; ++m2)
      #pragma unroll
      for (int n2 = 0; n2 < 2; ++n2)
        o[m2][n2] = MFMA16(pa[m2][ks], __builtin_bit_cast(v8bf, bvu[n2][ks]),
                           o[m2][n2]);

  #pragma unroll
  for (int m2 = 0; m2 < 4; ++m2){
    #pragma unroll
    for (int n2 = 0; n2 < 2; ++n2){
      #pragma unroll
      for (int r = 0; r < 4; ++r){
        int row = m2*16 + lg*4 + r;
        if (row < 49){
          float val = o[m2][n2][r] * rs_[m2][r];
          aout[(w * 49 + row) * 192 + h * 32 + n2*16 + lr] = f2bf(val);
        }
      }
    }
  }
}

// ------------------------------ launcher -----------------------------------
extern "C" void kernel_launch(void* const* d_in, const int* in_sizes, int n_in,
                              void* d_out, int out_size, void* d_ws, size_t ws_size,
                              hipStream_t stream){
  const float* x     = (const float*)d_in[0];
  const float* n1g   = (const float*)d_in[1];
  const float* n1b   = (const float*)d_in[2];
  const float* qkvw  = (const float*)d_in[3];
  const float* qkvb  = (const float*)d_in[4];
  const float* rpb   = (const float*)d_in[5];
  const float* projw = (const float*)d_in[6];
  const float* projb = (const float*)d_in[7];
  const float* n2g   = (const float*)d_in[8];
  const float* n2b   = (const float*)d_in[9];
  const float* fc1w  = (const float*)d_in[10];
  const float* fc1b  = (const float*)d_in[11];
  const float* fc2w  = (const float*)d_in[12];
  const float* fc2b  = (const float*)d_in[13];
  float* out = (float*)d_out;

  // d_ws layout (617.5 MB, same as known-good round 0):
  //   bufA @ 0        : qkv (462.4MB) -> later h1 chunks (308.3MB)
  //   bufB @ 462.4MB  : xw -> attn_out -> xln2 (154.1MB)
  //   weights @ 616.6MB : bf16 copies (~0.9MB)
  // bias+mask table (393KB) lives in d_out scratch until proj overwrites it.
  char* ws  = (char*)d_ws;
  u16* bufA = (u16*)ws;
  u16* bufB = (u16*)(ws + 462422016L);
  u16* wq   = (u16*)(ws + 616562688L);
  u16* wp   = wq + 110592;
  u16* w1   = wp + 36864;
  u16* w2   = w1 + 147456;
  float* bmt = (float*)d_out;   // 98304 floats, consumed by attn before proj

  convk<<<432, 256, 0, stream>>>(qkvw,  wq, 110592);
  convk<<<144, 256, 0, stream>>>(projw, wp, 36864);
  convk<<<576, 256, 0, stream>>>(fc1w,  w1, 147456);
  convk<<<576, 256, 0, stream>>>(fc2w,  w2, 147456);
  bmt_k<<<384, 256, 0, stream>>>(rpb, bmt);

  // LN1 + shift + window partition
  ln_kern<true><<<100352, 256, 0, stream>>>(x, n1g, n1b, bufB);
  // qkv (M=401408, N=576, K=192) -> permuted q,k,v
  gemm_bt<0><<<dim3(3136, 9), 256, 0, stream>>>(bufB, 192, 0, wq, 192, 192,
                                                qkvb, bufA, nullptr, nullptr, 0);
  // windowed attention
  attn_k<<<12288, 256, 0, stream>>>(bufA, bmt, bufB);
  // proj (N=192) + scatter + residual -> d_out
  gemm_bt<1><<<dim3(3136, 3), 256, 0, stream>>>(bufB, 192, 0, wp, 192, 192,
                                                projb, nullptr, out, x, 0);
  // LN2
  ln_kern<false><<<100352, 256, 0, stream>>>(out, n2g, n2b, bufB);
  // MLP in 2 token-chunks (h1 chunk reuses bufA)
  for (int c = 0; c < 2; ++c){
    long off = (long)c * 200704;
    gemm_bt<2><<<dim3(1568, 12), 256, 0, stream>>>(bufB, 192, off, w1, 192, 192,
                                                   fc1b, bufA, nullptr, nullptr, 0);
    gemm_bt<3><<<dim3(1568, 3), 256, 0, stream>>>(bufA, 768, 0, w2, 768, 768,
                                                  fc2b, nullptr, out, nullptr, off);
  }
}

// Round 3
// 1677.685 us; speedup vs baseline: 1.3377x; 1.1663x over previous
//
#include <hip/hip_runtime.h>
#include <stdint.h>
#include <math.h>

// ---------------------------------------------------------------------------
// Swin block, MI355X. B=32 H=W=112 C=192 NH=6 hd=32 WS=7 SS=3 -> 8192 windows,
// 49 tokens each, 401408 token-rows total.
// R2: GEMM grid-swap (col-blocks dispatch adjacently -> A-tile L3 reuse),
//     32-bit epilogue index math, bias as MFMA C-init, incremental staging
//     cursors; attn: no max-pass (bounded scores), b128 bias-table C-init,
//     row-sums via ones-column MFMA, 32KB XOR-swizzled P-LDS; LN 4 tok/wave.
// ---------------------------------------------------------------------------

typedef unsigned short u16;
typedef unsigned int   u32;
typedef __bf16 v8bf __attribute__((ext_vector_type(8)));
typedef float  v4f  __attribute__((ext_vector_type(4)));
typedef u16    v8u16 __attribute__((ext_vector_type(8)));
typedef u16    v4u16 __attribute__((ext_vector_type(4)));

#define MFMA16(a,b,c) __builtin_amdgcn_mfma_f32_16x16x32_bf16(a,b,c,0,0,0)

#define HSTR 77070336L          // elems per q/k/v array (8192*6*49*32)

__device__ __forceinline__ u16 f2bf(float f){
  u32 u = __builtin_bit_cast(u32, f);
  u32 r = u + 0x7FFFu + ((u >> 16) & 1u);   // RNE
  return (u16)(r >> 16);
}

__device__ __forceinline__ void async16(void* lds, const void* g){
  __builtin_amdgcn_global_load_lds(
      (__attribute__((address_space(1))) void*)(g),
      (__attribute__((address_space(3))) void*)(lds), 16, 0, 0);
}

// ------------------------------ weight convert -----------------------------
__global__ __launch_bounds__(256) void convk(const float* __restrict__ s,
                                             u16* __restrict__ d, int n){
  int i = blockIdx.x * 256 + threadIdx.x;
  if (i < n) d[i] = f2bf(s[i]);
}

// -------------------- fused rel-pos-bias + shift-mask table ----------------
// layout: [cls][h][m][n][lr][lg*4+r]  (matches MFMA C fragment, b128/lane)
__global__ __launch_bounds__(256)
void bmt_k(const float* __restrict__ rpb, float* __restrict__ bmt){
  int idx = blockIdx.x * 256 + threadIdx.x;      // 98304 total
  int r  = idx & 3, lg = (idx >> 2) & 3, lr = (idx >> 4) & 15;
  int n  = (idx >> 8) & 3, m = (idx >> 10) & 3;
  int t  = idx >> 12; int h = t % 6, cls = t / 6;
  int row = m*16 + lg*4 + r, col = n*16 + lr;
  float v;
  if (row >= 49 || col >= 49){
    v = -1e30f;
  } else {
    int i1 = row / 7, j1 = row - i1 * 7;
    int i2 = col / 7, j2 = col - i2 * 7;
    int ridx = (i1 - i2 + 6) * 13 + (j1 - j2 + 6);
    v = rpb[ridx * 6 + h];
    int lh1 = (cls & 2) ? (i1 < 4 ? 1 : 2) : 0;
    int lw1 = (cls & 1) ? (j1 < 4 ? 1 : 2) : 0;
    int lh2 = (cls & 2) ? (i2 < 4 ? 1 : 2) : 0;
    int lw2 = (cls & 1) ? (j2 < 4 ? 1 : 2) : 0;
    if (lh1 * 3 + lw1 != lh2 * 3 + lw2) v -= 100.f;
  }
  bmt[idx] = v;
}

// ----------------------- LayerNorm (optionally gathered) -------------------
// 16 lanes per token, 4 tokens per wave; lane handles 12 channels (3 float4).
template<bool GATHER>
__global__ __launch_bounds__(256)
void ln_kern(const float* __restrict__ x, const float* __restrict__ g,
             const float* __restrict__ b, u16* __restrict__ o){
  const int ts  = threadIdx.x >> 4;
  const int l16 = threadIdx.x & 15;
  const int r   = blockIdx.x * 16 + ts;          // < 401408
  const float* src;
  if (GATHER){
    u32 wdx = (u32)r / 49u; int nn = r - (int)wdx * 49;
    int bb = (int)(wdx >> 8); int wl = (int)(wdx & 255);
    int wh = wl >> 4, wwi = wl & 15;
    int ii = (int)((u32)nn / 7u), jj = nn - ii * 7;
    int th = wh * 7 + ii + 3;  if (th >= 112) th -= 112;
    int tw = wwi * 7 + jj + 3; if (tw >= 112) tw -= 112;
    src = x + (u32)(bb * 12544 + th * 112 + tw) * 192u;
  } else {
    src = x + (u32)r * 192u;
  }
  const float4 a0 = *(const float4*)(src + l16*12);
  const float4 a1 = *(const float4*)(src + l16*12 + 4);
  const float4 a2 = *(const float4*)(src + l16*12 + 8);
  float sm = ((a0.x+a0.y)+(a0.z+a0.w)) + ((a1.x+a1.y)+(a1.z+a1.w))
           + ((a2.x+a2.y)+(a2.z+a2.w));
  float sq = ((a0.x*a0.x+a0.y*a0.y)+(a0.z*a0.z+a0.w*a0.w))
           + ((a1.x*a1.x+a1.y*a1.y)+(a1.z*a1.z+a1.w*a1.w))
           + ((a2.x*a2.x+a2.y*a2.y)+(a2.z*a2.z+a2.w*a2.w));
  #pragma unroll
  for (int d = 1; d < 16; d <<= 1){
    sm += __shfl_xor(sm, d, 64);
    sq += __shfl_xor(sq, d, 64);
  }
  float mean = sm * (1.f/192.f);
  float var  = sq * (1.f/192.f) - mean * mean;
  float rs   = rsqrtf(var + 1e-5f);
  const float4 g0 = *(const float4*)(g + l16*12);
  const float4 g1 = *(const float4*)(g + l16*12 + 4);
  const float4 g2 = *(const float4*)(g + l16*12 + 8);
  const float4 b0 = *(const float4*)(b + l16*12);
  const float4 b1 = *(const float4*)(b + l16*12 + 4);
  const float4 b2 = *(const float4*)(b + l16*12 + 8);
  u16* dst = o + (u32)r * 192u + l16 * 12;
  v4u16 w0, w1, w2;
  w0[0]=f2bf((a0.x-mean)*rs*g0.x+b0.x); w0[1]=f2bf((a0.y-mean)*rs*g0.y+b0.y);
  w0[2]=f2bf((a0.z-mean)*rs*g0.z+b0.z); w0[3]=f2bf((a0.w-mean)*rs*g0.w+b0.w);
  w1[0]=f2bf((a1.x-mean)*rs*g1.x+b1.x); w1[1]=f2bf((a1.y-mean)*rs*g1.y+b1.y);
  w1[2]=f2bf((a1.z-mean)*rs*g1.z+b1.z); w1[3]=f2bf((a1.w-mean)*rs*g1.w+b1.w);
  w2[0]=f2bf((a2.x-mean)*rs*g2.x+b2.x); w2[1]=f2bf((a2.y-mean)*rs*g2.y+b2.y);
  w2[2]=f2bf((a2.z-mean)*rs*g2.z+b2.z); w2[3]=f2bf((a2.w-mean)*rs*g2.w+b2.w);
  *(v4u16*)(dst)     = w0;
  *(v4u16*)(dst + 4) = w1;
  *(v4u16*)(dst + 8) = w2;
}

// ------------------------------- GEMM (A @ W^T) ----------------------------
// BM=128, BN=64, BK=192/stage. grid: x = col-block (adjacent dispatch ->
// A-tile L3 reuse), y = row-block. Bias folded into acc init.
template<int EPI>
__global__ __launch_bounds__(256)
void gemm_bt(const u16* __restrict__ A, int ldA, int aRowOff,
             const u16* __restrict__ W, int ldW, int K,
             const float* __restrict__ bias,
             u16* __restrict__ ob, float* __restrict__ of,
             const float* __restrict__ xres, int oRowOff){
  __shared__ __align__(16) u16 sA[128 * 200];
  __shared__ __align__(16) u16 sW[64 * 200];
  const int tid = threadIdx.x;
  const int wv = tid >> 6, lnn = tid & 63;
  const int lr = lnn & 15, lg = lnn >> 4;
  const int m0   = (int)blockIdx.y * 128;
  const int col0 = (int)blockIdx.x * 64;
  const int wr = wv >> 1, wc = wv & 1;

  const float b0v = bias[col0 + wc*32 + lr];
  const float b1v = bias[col0 + wc*32 + 16 + lr];
  v4f acc[4][2];
  #pragma unroll
  for (int m = 0; m < 4; ++m){
    acc[m][0] = (v4f){b0v, b0v, b0v, b0v};
    acc[m][1] = (v4f){b1v, b1v, b1v, b1v};
  }

  const int rA0 = (int)((u32)tid / 25u);
  const int cA0 = tid - rA0 * 25;
  const u32 aBase = (u32)(aRowOff + m0);
  const int nK = K / 192;
  for (int ks = 0; ks < nK; ++ks){
    if (ks) __syncthreads();
    const int k0 = ks * 192;
    // A tile: 128 rows x 25 chunks(16B); chunk 24 re-reads tail (keeps LDS linear)
    int ra = rA0, ca = cA0;
    #pragma unroll
    for (int it = 0; it < 12; ++it){
      int cc = (ca == 24) ? 23 : ca;
      async16((char*)sA + (size_t)(it * 256 + wv * 64) * 16,
              A + (aBase + (u32)ra) * (u32)ldA + (u32)(k0 + cc * 8));
      ra += 10; ca += 6; if (ca >= 25){ ca -= 25; ra += 1; }
    }
    if (wv < 2){
      int cc = (ca == 24) ? 23 : ca;
      async16((char*)sA + (size_t)(3072 + wv * 64) * 16,
              A + (aBase + (u32)ra) * (u32)ldA + (u32)(k0 + cc * 8));
    }
    // W tile: 64 rows x 25 chunks
    int rw = rA0, cw = cA0;
    #pragma unroll
    for (int it = 0; it < 6; ++it){
      int cc = (cw == 24) ? 23 : cw;
      async16((char*)sW + (size_t)(it * 256 + wv * 64) * 16,
              W + (u32)(col0 + rw) * (u32)ldW + (u32)(k0 + cc * 8));
      rw += 10; cw += 6; if (cw >= 25){ cw -= 25; rw += 1; }
    }
    if (wv == 0){
      int cc = (cw == 24) ? 23 : cw;
      async16((char*)sW + (size_t)1536 * 16,
              W + (u32)(col0 + rw) * (u32)ldW + (u32)(k0 + cc * 8));
    }
    __syncthreads();   // drains vmcnt(0) -> staged data visible

    #pragma unroll
    for (int kk = 0; kk < 6; ++kk){
      v8bf af[4], wf[2];
      #pragma unroll
      for (int m = 0; m < 4; ++m)
        af[m] = *(const v8bf*)&sA[(wr*64 + m*16 + lr) * 200 + kk*32 + lg*8];
      #pragma unroll
      for (int n = 0; n < 2; ++n)
        wf[n] = *(const v8bf*)&sW[(wc*32 + n*16 + lr) * 200 + kk*32 + lg*8];
      #pragma unroll
      for (int m = 0; m < 4; ++m)
        #pragma unroll
        for (int n = 0; n < 2; ++n)
          acc[m][n] = MFMA16(af[m], wf[n], acc[m][n]);
    }
  }

  // epilogue (32-bit index math).  D layout: row = 4*lg + r, col = lr
  #pragma unroll
  for (int m = 0; m < 4; ++m){
    #pragma unroll
    for (int n = 0; n < 2; ++n){
      #pragma unroll
      for (int r = 0; r < 4; ++r){
        const int lrow = m0 + wr*64 + m*16 + lg*4 + r;
        const int col  = col0 + wc*32 + n*16 + lr;
        float val = acc[m][n][r];
        if (EPI == 0){
          int which = (col >= 384) ? 2 : ((col >= 192) ? 1 : 0);
          int rem = col - which * 192;
          int hh = rem >> 5, dd = rem & 31;
          if (which == 0) val *= 0.17677669529663687f;  // hd^-0.5
          u32 wdx = (u32)lrow / 49u; u32 nn = (u32)lrow - wdx * 49u;
          ob[(u32)which * 77070336u + ((wdx*6u + (u32)hh)*49u + nn)*32u + (u32)dd]
              = f2bf(val);
        } else if (EPI == 1){
          u32 wdx = (u32)lrow / 49u; int nn = lrow - (int)wdx * 49;
          int bb = (int)(wdx >> 8); int wl = (int)(wdx & 255);
          int wh = wl >> 4, wwi = wl & 15;
          int ii = (int)((u32)nn / 7u), jj = nn - ii * 7;
          int th = wh * 7 + ii + 3;  if (th >= 112) th -= 112;
          int tw = wwi * 7 + jj + 3; if (tw >= 112) tw -= 112;
          u32 adr = (u32)(bb * 12544 + th * 112 + tw) * 192u + (u32)col;
          of[adr] = xres[adr] + val;
        } else if (EPI == 2){
          float gg = 0.5f * val * (1.0f + erff(val * 0.7071067811865475f));
          ob[(u32)lrow * 768u + (u32)col] = f2bf(gg);
        } else {
          of[(u32)(oRowOff + lrow) * 192u + (u32)col] += val;
        }
      }
    }
  }
}

// ------------------------------- attention ---------------------------------
// one wave per (window, head); 4 waves / block.  49 padded to 64.
// Scores are bounded (|qk|+|bias| << 80) -> no max-subtraction needed; masked
// entries (-100) and pads (-1e30) underflow exp to 0 exactly like softmax.
// P stored packed (pos = lr*4+n) with XOR swizzle; V fragment k-permuted to
// match; row-sums via a ones-column MFMA.
__global__ __launch_bounds__(256, 4)
void attn_k(const u16* __restrict__ qkv, const float* __restrict__ bmt,
            u16* __restrict__ aout){
  __shared__ __align__(16) u16 plds[4][64 * 64];   // 32 KB total
  const int wv = threadIdx.x >> 6, lnn = threadIdx.x & 63;
  const int lr = lnn & 15, lg = lnn >> 4;
  const u32 gid = (u32)blockIdx.x * 4u + (u32)wv;   // < 49152
  const u32 w = gid / 6u; const int h = (int)(gid - w * 6u);
  const u16* qb = qkv + (size_t)gid * 1568;
  const u16* kb = qb + HSTR;
  const u16* vb = kb + HSTR;

  // C-init = bias+mask table (b128 per lane, L2/L3-resident)
  const int wl = (int)(w & 255);
  const int cls = (((wl >> 4) == 15) ? 2 : 0) | (((wl & 15) == 15) ? 1 : 0);
  const float* bmv = bmt + ((u32)(cls * 6 + h) << 12);
  v4f s[4][4];
  #pragma unroll
  for (int m = 0; m < 4; ++m)
    #pragma unroll
    for (int n = 0; n < 4; ++n)
      s[m][n] = *(const v4f*)&bmv[(u32)(((m*4 + n)*16 + lr)*16 + lg*4)];

  // Q.K^T on top of bias
  v8bf aq[4], bk4[4];
  #pragma unroll
  for (int m = 0; m < 4; ++m) aq[m]  = *(const v8bf*)(qb + (m*16 + lr)*32 + lg*8);
  #pragma unroll
  for (int n = 0; n < 4; ++n) bk4[n] = *(const v8bf*)(kb + (n*16 + lr)*32 + lg*8);
  #pragma unroll
  for (int m = 0; m < 4; ++m)
    #pragma unroll
    for (int n = 0; n < 4; ++n) s[m][n] = MFMA16(aq[m], bk4[n], s[m][n]);

  // V fragments from global, k-permuted (pads multiply P==0 -> harmless)
  v8u16 bvu[2][2];
  #pragma unroll
  for (int n2 = 0; n2 < 2; ++n2)
    #pragma unroll
    for (int ksi = 0; ksi < 2; ++ksi)
      #pragma unroll
      for (int e = 0; e < 8; ++e){
        int kp = ksi * 32 + lg * 8 + e;
        int t  = (kp >> 2) + (kp & 3) * 16;
        bvu[n2][ksi][e] = vb[(u32)(t * 32 + n2 * 16 + lr)];
      }

  // P = exp(s), packed store (pos = lr*4+n), XOR-swizzled rows
  #pragma unroll
  for (int m = 0; m < 4; ++m)
    #pragma unroll
    for (int r = 0; r < 4; ++r){
      int row = m*16 + lg*4 + r;
      v4u16 pk;
      pk[0] = f2bf(__expf(s[m][0][r]));
      pk[1] = f2bf(__expf(s[m][1][r]));
      pk[2] = f2bf(__expf(s[m][2][r]));
      pk[3] = f2bf(__expf(s[m][3][r]));
      *(v4u16*)((char*)&plds[wv][0] + row*128 + ((lr*8) ^ ((row & 7) << 4))) = pk;
    }

  v8bf pa[4][2];
  #pragma unroll
  for (int m2 = 0; m2 < 4; ++m2)
    #pragma unroll
    for (int ksi = 0; ksi < 2; ++ksi){
      int row2 = m2*16 + lr;
      pa[m2][ksi] = *(const v8bf*)((const char*)&plds[wv][0] + row2*128 +
                                   ((ksi*64 + lg*16) ^ ((row2 & 7) << 4)));
    }

  // ones B-frag (col 0 only) for row-sums
  v8u16 onesu;
  #pragma unroll
  for (int e = 0; e < 8; ++e) onesu[e] = (lr == 0) ? (u16)0x3F80 : (u16)0;
  const v8bf onesf = __builtin_bit_cast(v8bf, onesu);

  const v4f zf = {0.f, 0.f, 0.f, 0.f};
  v4f o2[4][2], sacc[4];
  #pragma unroll
  for (int m2 = 0; m2 < 4; ++m2){
    o2[m2][0] = zf; o2[m2][1] = zf; sacc[m2] = zf;
  }
  #pragma unroll
  for (int ksi = 0; ksi < 2; ++ksi)
    #pragma unroll
    for (int m2 = 0; m2 < 4; ++m2){
      o2[m2][0] = MFMA16(pa[m2][ksi], __builtin_bit_cast(v8bf, bvu[0][ksi]), o2[m2][0]);
      o2[m2][1] = MFMA16(pa[m2][ksi], __builtin_bit_cast(v8bf, bvu[1][ksi]), o2[m2][1]);
      sacc[m2]  = MFMA16(pa[m2][ksi], onesf, sacc[m2]);
    }

  // broadcast row-sums (live in lanes lr==0) and normalize on store
  float inv[4][4];
  #pragma unroll
  for (int m2 = 0; m2 < 4; ++m2)
    #pragma unroll
    for (int r = 0; r < 4; ++r)
      inv[m2][r] = 1.0f / __shfl(sacc[m2][r], lnn & 48, 64);

  #pragma unroll
  for (int m2 = 0; m2 < 4; ++m2){
    #pragma unroll
    for (int n2 = 0; n2 < 2; ++n2){
      #pragma unroll
      for (int r = 0; r < 4; ++r){
        int row = m2*16 + lg*4 + r;
        if (row < 49){
          float val = o2[m2][n2][r] * inv[m2][r];
          aout[(w * 49u + (u32)row) * 192u + (u32)(h*32 + n2*16 + lr)] = f2bf(val);
        }
      }
    }
  }
}

// ------------------------------ launcher -----------------------------------
extern "C" void kernel_launch(void* const* d_in, const int* in_sizes, int n_in,
                              void* d_out, int out_size, void* d_ws, size_t ws_size,
                              hipStream_t stream){
  const float* x     = (const float*)d_in[0];
  const float* n1g   = (const float*)d_in[1];
  const float* n1b   = (const float*)d_in[2];
  const float* qkvw  = (const float*)d_in[3];
  const float* qkvb  = (const float*)d_in[4];
  const float* rpb   = (const float*)d_in[5];
  const float* projw = (const float*)d_in[6];
  const float* projb = (const float*)d_in[7];
  const float* n2g   = (const float*)d_in[8];
  const float* n2b   = (const float*)d_in[9];
  const float* fc1w  = (const float*)d_in[10];
  const float* fc1b  = (const float*)d_in[11];
  const float* fc2w  = (const float*)d_in[12];
  const float* fc2b  = (const float*)d_in[13];
  float* out = (float*)d_out;

  char* ws  = (char*)d_ws;
  u16* bufA = (u16*)ws;                       // qkv 462MB -> h1 chunks
  u16* bufB = (u16*)(ws + 462422016L);        // xw -> attn_out -> xln2
  u16* wq   = (u16*)(ws + 616562688L);
  u16* wp   = wq + 110592;
  u16* w1   = wp + 36864;
  u16* w2   = w1 + 147456;
  float* bmt = (float*)d_out;   // 98304 floats, consumed by attn before proj

  convk<<<432, 256, 0, stream>>>(qkvw,  wq, 110592);
  convk<<<144, 256, 0, stream>>>(projw, wp, 36864);
  convk<<<576, 256, 0, stream>>>(fc1w,  w1, 147456);
  convk<<<576, 256, 0, stream>>>(fc2w,  w2, 147456);
  bmt_k<<<384, 256, 0, stream>>>(rpb, bmt);

  // LN1 + shift + window partition
  ln_kern<true><<<25088, 256, 0, stream>>>(x, n1g, n1b, bufB);
  // qkv (M=401408, N=576, K=192) -> permuted q,k,v
  gemm_bt<0><<<dim3(9, 3136), 256, 0, stream>>>(bufB, 192, 0, wq, 192, 192,
                                                qkvb, bufA, nullptr, nullptr, 0);
  // windowed attention
  attn_k<<<12288, 256, 0, stream>>>(bufA, bmt, bufB);
  // proj (N=192) + scatter + residual -> d_out
  gemm_bt<1><<<dim3(3, 3136), 256, 0, stream>>>(bufB, 192, 0, wp, 192, 192,
                                                projb, nullptr, out, x, 0);
  // LN2
  ln_kern<false><<<25088, 256, 0, stream>>>(out, n2g, n2b, bufB);
  // MLP in 2 token-chunks (h1 chunk reuses bufA)
  for (int c = 0; c < 2; ++c){
    int off = c * 200704;
    gemm_bt<2><<<dim3(12, 1568), 256, 0, stream>>>(bufB, 192, off, w1, 192, 192,
                                                   fc1b, bufA, nullptr, nullptr, 0);
    gemm_bt<3><<<dim3(3, 1568), 256, 0, stream>>>(bufA, 768, 0, w2, 768, 768,
                                                  fc2b, nullptr, out, nullptr, off);
  }
}